// Round 2
// baseline (371.242 us; speedup 1.0000x reference)
//
#include <hip/hip_runtime.h>
#include <cstddef>

namespace {
constexpr int S = 512;
constexpr int B = 64;
constexpr int H = 768;
constexpr int T = 32;
constexpr int START = 30;
constexpr int END = 31;
}

// ---------------------------------------------------------------------------
// Kernel 1: emissions. emitT[b][s][t] = dot(emb[s,b,:], W[:,t]) + bias[t]
// ---------------------------------------------------------------------------
__global__ __launch_bounds__(256) void emit_gemm(const float* __restrict__ A,
                                                 const float* __restrict__ W,
                                                 const float* __restrict__ bias,
                                                 float* __restrict__ emitT) {
  __shared__ __align__(16) float At[64][64];  // [h][r], 16 KB
  __shared__ __align__(16) float Wl[64][32];  // [h][t], 8 KB
  const int tid = threadIdx.x;
  const int s = blockIdx.x;
  const int t = tid & 31;
  const int r0 = tid >> 5;
  float acc[8];
#pragma unroll
  for (int k = 0; k < 8; ++k) acc[k] = 0.f;
  const float* Ablk = A + (size_t)s * B * H;
  const int rr = tid >> 4;
  const int hh = (tid & 15) << 2;

  for (int hc = 0; hc < H; hc += 64) {
    {
      const float4* Wg = (const float4*)(W + hc * T);
      float4* Wd = (float4*)(&Wl[0][0]);
      Wd[tid] = Wg[tid];
      Wd[tid + 256] = Wg[tid + 256];
    }
#pragma unroll
    for (int i = 0; i < 4; ++i) {
      const int r = rr + 16 * i;
      float4 v = *(const float4*)(Ablk + (size_t)r * H + hc + hh);
      At[hh + 0][r] = v.x;
      At[hh + 1][r] = v.y;
      At[hh + 2][r] = v.z;
      At[hh + 3][r] = v.w;
    }
    __syncthreads();
#pragma unroll 8
    for (int h = 0; h < 64; ++h) {
      const float w = Wl[h][t];
      const float4* ap = (const float4*)(&At[h][r0 * 8]);
      float4 a0 = ap[0];
      float4 a1 = ap[1];
      acc[0] = fmaf(a0.x, w, acc[0]);
      acc[1] = fmaf(a0.y, w, acc[1]);
      acc[2] = fmaf(a0.z, w, acc[2]);
      acc[3] = fmaf(a0.w, w, acc[3]);
      acc[4] = fmaf(a1.x, w, acc[4]);
      acc[5] = fmaf(a1.y, w, acc[5]);
      acc[6] = fmaf(a1.z, w, acc[6]);
      acc[7] = fmaf(a1.w, w, acc[7]);
    }
    __syncthreads();
  }
  const float bb = bias[t];
#pragma unroll
  for (int k = 0; k < 8; ++k) {
    const int b = r0 * 8 + k;
    emitT[((size_t)b * S + s) * T + t] = acc[k] + bb;
  }
}

// ---------------------------------------------------------------------------
// Scan step functions. Arithmetic replicates the reference exactly:
//   v[prev] = (trans[cur][prev] + emit) + dp[prev]   (left-assoc adds)
// alpha: dp[cur] = m + log(sum exp(v-m));  viterbi: dp[cur] = max(v),
// argmax with FIRST-index tie-break (np.argmax semantics).
// Wave-synchronous via LDS; asm memory fences stop compiler reordering.
// ---------------------------------------------------------------------------
__device__ __forceinline__ void astep(float e, const float* tr, float* dp,
                                      int cur, int h) {
  asm volatile("" ::: "memory");
  const float* dh = dp + h * 16;
  float v[16];
#pragma unroll
  for (int j = 0; j < 4; ++j) {
    float4 d = *(const float4*)(dh + 4 * j);
    v[4 * j + 0] = (tr[4 * j + 0] + e) + d.x;
    v[4 * j + 1] = (tr[4 * j + 1] + e) + d.y;
    v[4 * j + 2] = (tr[4 * j + 2] + e) + d.z;
    v[4 * j + 3] = (tr[4 * j + 3] + e) + d.w;
  }
  float m = -3.0e38f;
#pragma unroll
  for (int i = 0; i < 16; ++i) m = fmaxf(m, v[i]);
  m = fmaxf(m, __shfl_xor(m, 32));
  float sum = 0.f;
#pragma unroll
  for (int i = 0; i < 16; ++i) sum += __expf(v[i] - m);
  sum += __shfl_xor(sum, 32);
  const float nd = m + __logf(sum);
  if (h == 0) dp[cur] = nd;
  asm volatile("" ::: "memory");
}

__device__ __forceinline__ void vstep(float e, const float* tr, float* dp,
                                      unsigned char* bprow, int cur, int h) {
  asm volatile("" ::: "memory");
  const float* dh = dp + h * 16;
  float best = -3.0e38f;
  int arg = 0;
#pragma unroll
  for (int j = 0; j < 4; ++j) {
    float4 d = *(const float4*)(dh + 4 * j);
    float vv[4] = {(tr[4 * j + 0] + e) + d.x, (tr[4 * j + 1] + e) + d.y,
                   (tr[4 * j + 2] + e) + d.z, (tr[4 * j + 3] + e) + d.w};
#pragma unroll
    for (int k = 0; k < 4; ++k) {
      const int p = h * 16 + 4 * j + k;
      if (vv[k] > best) { best = vv[k]; arg = p; }  // ascending p: first-max
    }
  }
  const float ob = __shfl_xor(best, 32);
  const int oa = __shfl_xor(arg, 32);
  if (ob > best || (ob == best && oa < arg)) { best = ob; arg = oa; }
  if (h == 0) {
    dp[cur] = best;  // == max((tr+e)+dp), ref rounding
    bprow[cur] = (unsigned char)arg;
  }
  asm volatile("" ::: "memory");
}

// ---------------------------------------------------------------------------
// Shared epilogues
// ---------------------------------------------------------------------------
__device__ __forceinline__ void alpha_epilogue(const float* dp, float g,
                                               const float* trans, float* out,
                                               int lane, int b) {
  const float v = (lane < T) ? dp[lane] + trans[END * T + lane] : -3.0e38f;
  float mx = v;
#pragma unroll
  for (int o = 32; o >= 1; o >>= 1) mx = fmaxf(mx, __shfl_xor(mx, o));
  float sm = (lane < T) ? __expf(v - mx) : 0.f;
#pragma unroll
  for (int o = 32; o >= 1; o >>= 1) sm += __shfl_xor(sm, o);
  const float lp = mx + __logf(sm);
#pragma unroll
  for (int o = 32; o >= 1; o >>= 1) g += __shfl_xor(g, o);
  if (lane == 0) out[b] = lp - g;
}

__device__ __forceinline__ void vit_epilogue(const float* dp,
                                             const unsigned char* bp,
                                             unsigned char* pathb,
                                             const float* trans, float* out,
                                             int lane, int b) {
  float v = (lane < T) ? dp[lane] + trans[END * T + lane] : -3.0e38f;
  int a = lane;
#pragma unroll
  for (int o = 32; o >= 1; o >>= 1) {
    const float ov = __shfl_xor(v, o);
    const int oa = __shfl_xor(a, o);
    if (ov > v || (ov == v && oa < a)) { v = ov; a = oa; }
  }
  if (lane == 0) out[64 + 32768 + b] = v;
  if (lane == 0) {
    int tag = a;
    for (int s = S - 1; s >= 0; --s) {
      pathb[s] = (unsigned char)tag;
      tag = bp[s * T + tag];
    }
  }
  asm volatile("" ::: "memory");
  for (int i = lane; i < S; i += 64) out[64 + b * S + i] = (float)pathb[i];
}

// ---------------------------------------------------------------------------
// Kernel 2 (primary): scan reading precomputed emitT from d_ws.
// ---------------------------------------------------------------------------
__global__ __launch_bounds__(64) void crf_scan(const float* __restrict__ emitT,
                                               const int* __restrict__ labels,
                                               const float* __restrict__ trans,
                                               float* __restrict__ out) {
  __shared__ __align__(16) float dp[T];
  __shared__ unsigned char bp[S * T];
  __shared__ unsigned char pathb[S];
  const int lane = threadIdx.x;
  const int b = blockIdx.x & 63;
  const bool is_vit = blockIdx.x >= 64;
  const int cur = lane & 31;
  const int h = lane >> 5;

  float tr[16];
#pragma unroll
  for (int j = 0; j < 4; ++j) {
    float4 v = *(const float4*)(trans + cur * T + h * 16 + 4 * j);
    tr[4 * j + 0] = v.x; tr[4 * j + 1] = v.y;
    tr[4 * j + 2] = v.z; tr[4 * j + 3] = v.w;
  }
  if (lane < T) dp[lane] = (lane == START) ? 0.f : -100000.0f;

  const float* ebase = emitT + (size_t)b * (S * T);
  const float* eb = ebase + cur;

  if (!is_vit) {
    float e0 = eb[0 * T], e1 = eb[1 * T], e2 = eb[2 * T], e3 = eb[3 * T];
    for (int s = 0; s < S; s += 4) {
      const float n0 = eb[((s + 4) & (S - 1)) * T];
      const float n1 = eb[((s + 5) & (S - 1)) * T];
      const float n2 = eb[((s + 6) & (S - 1)) * T];
      const float n3 = eb[((s + 7) & (S - 1)) * T];
      astep(e0, tr, dp, cur, h);
      astep(e1, tr, dp, cur, h);
      astep(e2, tr, dp, cur, h);
      astep(e3, tr, dp, cur, h);
      e0 = n0; e1 = n1; e2 = n2; e3 = n3;
    }
    float g = 0.f;
    for (int s = lane; s < S; s += 64) {
      const int c = labels[s * B + b];
      const int p = (s == 0) ? START : labels[(s - 1) * B + b];
      g += trans[c * T + p] + ebase[s * T + c];
    }
    if (lane == 63) g += trans[END * T + labels[(S - 1) * B + b]];
    alpha_epilogue(dp, g, trans, out, lane, b);
  } else {
    float e0 = eb[0 * T], e1 = eb[1 * T], e2 = eb[2 * T], e3 = eb[3 * T];
    for (int s = 0; s < S; s += 4) {
      const float n0 = eb[((s + 4) & (S - 1)) * T];
      const float n1 = eb[((s + 5) & (S - 1)) * T];
      const float n2 = eb[((s + 6) & (S - 1)) * T];
      const float n3 = eb[((s + 7) & (S - 1)) * T];
      vstep(e0, tr, dp, bp + (s + 0) * T, cur, h);
      vstep(e1, tr, dp, bp + (s + 1) * T, cur, h);
      vstep(e2, tr, dp, bp + (s + 2) * T, cur, h);
      vstep(e3, tr, dp, bp + (s + 3) * T, cur, h);
      e0 = n0; e1 = n1; e2 = n2; e3 = n3;
    }
    vit_epilogue(dp, bp, pathb, trans, out, lane, b);
  }
}

// ---------------------------------------------------------------------------
// Fallback (no workspace): compute emissions inline each step. Slow but
// correct; only used if ws_size < 4 MiB. Its duration doubles as a
// diagnostic that d_ws was too small.
// ---------------------------------------------------------------------------
__device__ __forceinline__ float emit_inline(const float* __restrict__ emb,
                                             const float* __restrict__ W,
                                             const float* __restrict__ bias,
                                             int b, int s, int cur, int h) {
  const float* er = emb + ((size_t)s * B + b) * H + h * (H / 2);
  const float* wc = W + (size_t)h * (H / 2) * T + cur;
  float acc = 0.f;
  for (int k = 0; k < H / 2; k += 4) {
    float4 ev = *(const float4*)(er + k);
    acc += ev.x * wc[(k + 0) * T];
    acc += ev.y * wc[(k + 1) * T];
    acc += ev.z * wc[(k + 2) * T];
    acc += ev.w * wc[(k + 3) * T];
  }
  acc += __shfl_xor(acc, 32);
  return acc + bias[cur];
}

__global__ __launch_bounds__(64) void crf_fused(const float* __restrict__ emb,
                                                const float* __restrict__ W,
                                                const float* __restrict__ bias,
                                                const int* __restrict__ labels,
                                                const float* __restrict__ trans,
                                                float* __restrict__ out) {
  __shared__ __align__(16) float dp[T];
  __shared__ unsigned char bp[S * T];
  __shared__ unsigned char pathb[S];
  const int lane = threadIdx.x;
  const int b = blockIdx.x & 63;
  const bool is_vit = blockIdx.x >= 64;
  const int cur = lane & 31;
  const int h = lane >> 5;

  float tr[16];
#pragma unroll
  for (int j = 0; j < 4; ++j) {
    float4 v = *(const float4*)(trans + cur * T + h * 16 + 4 * j);
    tr[4 * j + 0] = v.x; tr[4 * j + 1] = v.y;
    tr[4 * j + 2] = v.z; tr[4 * j + 3] = v.w;
  }
  if (lane < T) dp[lane] = (lane == START) ? 0.f : -100000.0f;

  if (!is_vit) {
    for (int s = 0; s < S; ++s) {
      const float e = emit_inline(emb, W, bias, b, s, cur, h);
      astep(e, tr, dp, cur, h);
    }
    float g = 0.f;
    for (int s = lane; s < S; s += 64) {
      const int c = labels[s * B + b];
      const int p = (s == 0) ? START : labels[(s - 1) * B + b];
      const float* er = emb + ((size_t)s * B + b) * H;
      const float* wc = W + c;
      float acc = 0.f;
      for (int k = 0; k < H; k += 4) {
        float4 ev = *(const float4*)(er + k);
        acc += ev.x * wc[(k + 0) * T];
        acc += ev.y * wc[(k + 1) * T];
        acc += ev.z * wc[(k + 2) * T];
        acc += ev.w * wc[(k + 3) * T];
      }
      g += trans[c * T + p] + acc + bias[c];
    }
    if (lane == 63) g += trans[END * T + labels[(S - 1) * B + b]];
    alpha_epilogue(dp, g, trans, out, lane, b);
  } else {
    for (int s = 0; s < S; ++s) {
      const float e = emit_inline(emb, W, bias, b, s, cur, h);
      vstep(e, tr, dp, bp + s * T, cur, h);
    }
    vit_epilogue(dp, bp, pathb, trans, out, lane, b);
  }
}

// ---------------------------------------------------------------------------
extern "C" void kernel_launch(void* const* d_in, const int* in_sizes, int n_in,
                              void* d_out, int out_size, void* d_ws,
                              size_t ws_size, hipStream_t stream) {
  const float* emb = (const float*)d_in[0];
  const int* labels = (const int*)d_in[1];
  const float* W = (const float*)d_in[2];
  const float* bias = (const float*)d_in[3];
  const float* trans = (const float*)d_in[4];
  float* out = (float*)d_out;

  const size_t need = (size_t)B * S * T * sizeof(float);  // 4 MiB
  if (ws_size >= need) {
    float* emitT = (float*)d_ws;
    emit_gemm<<<S, 256, 0, stream>>>(emb, W, bias, emitT);
    crf_scan<<<2 * B, 64, 0, stream>>>(emitT, labels, trans, out);
  } else {
    crf_fused<<<2 * B, 64, 0, stream>>>(emb, W, bias, labels, trans, out);
  }
}